// Round 5
// baseline (207.447 us; speedup 1.0000x reference)
//
#include <hip/hip_runtime.h>

// SpMM: out[i,d] = sum_{e: rows[e]==i} vals[e] * x[cols[e], d]
// N=100000 nodes, E=1600000 edges, DIM=32, fp32.
//
// v6: v5 + XCC_ID-exact sub-bucket selection in the scatter.
//  v5 post-mortem: scatter WRITE_SIZE 63 MB vs ~19 MB logical -> partial-line
//  write-backs because sub=blockIdx&7 drifts from the real block->XCD mapping
//  (dynamic dispatch backfill), so one tail line gets dirtied in several
//  non-coherent L2s. v6 reads the REAL XCD via s_getreg(HW_REG_XCC_ID)
//  [HW-verified on MI355X, learn_hip m09]: each (bucket,sub) tail line is
//  owned by exactly one XCD's L2, fills all 8 entries, writes back once.
//  Also: counter padding 64B -> 4B (atomics resolve at the memory-side
//  coherent point; padding bought nothing and cost 750 KB memset).
//  Pipeline unchanged otherwise:
//    pass1 scatter (XCC-split)  pass2 per-bucket counting sort (in place)
//    pass3 register row-gather (writes every out element; no out memset)
//    pass4 rare overflow apply
//
//  ws layout (~20.3 MB):
//   [0      .. 1KB)    : ocount
//   [1KB    .. ~51KB)  : counters, NB*NSUB x int
//   [~51KB  .. ~307KB) : overflow list, OCAP x int4 {r,c,valbits,_}
//   [~307KB .. ~1.1MB) : rowinfo, N x int2 {start, cnt}
//   [~1.1MB .. ~20.3MB): buckets, NB x BTOT x int2 (sorted in place)

#define N_NODES 100000
#define N_EDGES 1600000
#define DIM 32

#define RB    64                         // rows per bucket
#define NB    ((N_NODES + RB - 1) / RB)  // 1563
#define NSUB  8                          // sub-buckets = XCDs
#define CAP   192                        // per (bucket,sub); mean 128, +5.7 sigma
#define BTOT  (NSUB * CAP)               // 1536 entries per bucket
#define OCAP  16384

#define OFF_COUNTS   1024
#define OFF_OVER     ((OFF_COUNTS + NB * NSUB * 4 + 63) & ~63)   // ~51KB
#define OFF_ROWINFO  (OFF_OVER + OCAP * 16)
#define OFF_BUCKETS  (OFF_ROWINFO + N_NODES * 8)
#define WS_NEEDED    ((size_t)OFF_BUCKETS + (size_t)NB * BTOT * 8)

// ---------- fallback: original verified kernel (thread per (edge,dim)) ----------
__global__ __launch_bounds__(256) void spmm_atomic_kernel(
    const int* __restrict__ rows,
    const int* __restrict__ cols,
    const float* __restrict__ vals,
    const float* __restrict__ x,
    float* __restrict__ out)
{
    const long long idx = (long long)blockIdx.x * blockDim.x + threadIdx.x;
    const long long total = (long long)N_EDGES * DIM;
    if (idx >= total) return;

    const int e = (int)(idx >> 5);
    const int d = (int)(idx & 31);

    const int r   = rows[e];
    const int c   = cols[e];
    const float v = vals[e];

    const float xv = x[(long long)c * DIM + d];
    atomicAdd(&out[(long long)r * DIM + d], v * xv);
}

// ---------- pass 1: scatter edges into (bucket, XCD) segments ----------
__global__ __launch_bounds__(256) void spmm_scatter_bucket(
    const int* __restrict__ rows,
    const int* __restrict__ cols,
    const float* __restrict__ vals,
    int* __restrict__ ws_counts,     // NB*NSUB ints
    int2* __restrict__ buckets,      // NB x BTOT
    int* __restrict__ ocount,
    int4* __restrict__ overflow)
{
    const int e = blockIdx.x * blockDim.x + threadIdx.x;
    if (e >= N_EDGES) return;

    // real XCD id: tail lines of sub-bucket s are only touched by XCD s's L2
    unsigned xcc;
    asm volatile("s_getreg_b32 %0, hwreg(HW_REG_XCC_ID)" : "=s"(xcc));
    const int sub = (int)(xcc & (NSUB - 1));

    const int r = rows[e];
    const int c = cols[e];
    const int vb = __float_as_int(vals[e]);

    const int b  = r >> 6;                 // bucket = r / RB
    const int ci = b * NSUB + sub;

    const int pos = atomicAdd(&ws_counts[ci], 1);
    if (pos < CAP) {
        buckets[(size_t)ci * CAP + pos] = make_int2(((r & (RB - 1)) << 17) | c, vb);
    } else {
        const int op = atomicAdd(ocount, 1);
        if (op < OCAP) overflow[op] = make_int4(r, c, vb, 0);
    }
}

// ---------- pass 2: per-bucket counting sort by local row (in place) ----------
__global__ __launch_bounds__(256) void spmm_bucket_sort(
    const int* __restrict__ ws_counts,
    int2* __restrict__ buckets,
    int2* __restrict__ rowinfo)
{
    __shared__ int2 ent[BTOT];      // 12.3 KB staging of the whole bucket
    __shared__ int  hist[RB];
    __shared__ int  startx[RB];
    __shared__ int  cursor[RB];
    __shared__ int  scnt[NSUB];

    const int b   = blockIdx.x;
    const int tid = threadIdx.x;

    if (tid < NSUB) {
        int c0 = ws_counts[b * NSUB + tid];
        scnt[tid] = c0 < CAP ? c0 : CAP;
    }
    if (tid < RB) hist[tid] = 0;
    __syncthreads();

    const int g    = tid >> 5;
    const int lane = tid & 31;
    int base = 0;
    #pragma unroll
    for (int s = 0; s < NSUB; ++s) if (s < g) base += scnt[s];
    const int n = scnt[g];
    const int2* __restrict__ seg = buckets + (size_t)(b * NSUB + g) * CAP;

    // stage entries to LDS + row histogram (int LDS atomics: HW ds_add)
    for (int k = lane; k < n; k += 32) {
        const int2 e = seg[k];
        ent[base + k] = e;
        atomicAdd(&hist[e.x >> 17], 1);
    }
    __syncthreads();

    // exclusive scan over 64 row counts (Hillis-Steele in LDS)
    int myh = 0;
    if (tid < RB) { myh = hist[tid]; startx[tid] = myh; }
    __syncthreads();
    for (int off = 1; off < RB; off <<= 1) {
        int v = 0;
        if (tid < RB) { v = startx[tid]; if (tid >= off) v += startx[tid - off]; }
        __syncthreads();
        if (tid < RB) startx[tid] = v;
        __syncthreads();
    }
    int myexcl = 0;
    if (tid < RB) { myexcl = startx[tid] - myh; cursor[tid] = myexcl; }
    __syncthreads();

    // re-scatter: row-contiguous, written back into this bucket's own slice
    int2* __restrict__ dst = buckets + (size_t)b * BTOT;
    for (int k = lane; k < n; k += 32) {
        const int2 e = ent[base + k];
        const int pos = atomicAdd(&cursor[e.x >> 17], 1);
        dst[pos] = make_int2(e.x & 0x1FFFF, e.y);   // strip lrow: store (col, valbits)
    }

    if (tid < RB) {
        const int r = b * RB + tid;
        if (r < N_NODES) rowinfo[r] = make_int2(b * BTOT + myexcl, myh);
    }
}

// ---------- pass 3: register-accumulating row gather (v2-proven shape) ----------
__global__ __launch_bounds__(256) void spmm_row_gather(
    const int2* __restrict__ rowinfo,
    const int2* __restrict__ sorted,
    const float* __restrict__ x,
    float* __restrict__ out)
{
    const int d = threadIdx.x & 31;
    const int r = (blockIdx.x << 3) + (threadIdx.x >> 5);
    if (r >= N_NODES) return;

    const int2 ri = rowinfo[r];
    const int2* __restrict__ seg = sorted + ri.x;
    const int cnt = ri.y;

    float acc = 0.f;
    int k = 0;
    for (; k + 3 < cnt; k += 4) {
        const int2 e0 = seg[k + 0];
        const int2 e1 = seg[k + 1];
        const int2 e2 = seg[k + 2];
        const int2 e3 = seg[k + 3];
        const float x0 = x[e0.x * DIM + d];
        const float x1 = x[e1.x * DIM + d];
        const float x2 = x[e2.x * DIM + d];
        const float x3 = x[e3.x * DIM + d];
        acc = fmaf(__int_as_float(e0.y), x0, acc);
        acc = fmaf(__int_as_float(e1.y), x1, acc);
        acc = fmaf(__int_as_float(e2.y), x2, acc);
        acc = fmaf(__int_as_float(e3.y), x3, acc);
    }
    for (; k < cnt; ++k) {
        const int2 e0 = seg[k];
        acc = fmaf(__int_as_float(e0.y), x[e0.x * DIM + d], acc);
    }

    out[r * DIM + d] = acc;   // covers every row (cnt==0 -> 0); no out memset
}

// ---------- pass 4: apply rare overflow edges (normally empty) ----------
__global__ __launch_bounds__(256) void spmm_overflow_apply(
    const int* __restrict__ ocount,
    const int4* __restrict__ overflow,
    const float* __restrict__ x,
    float* __restrict__ out)
{
    int n = *ocount;
    if (n > OCAP) n = OCAP;
    const long long total = (long long)n * DIM;
    for (long long idx = (long long)blockIdx.x * blockDim.x + threadIdx.x;
         idx < total; idx += (long long)gridDim.x * blockDim.x) {
        const int e = (int)(idx >> 5);
        const int d = (int)(idx & 31);
        const int4 t = overflow[e];
        atomicAdd(&out[(long long)t.x * DIM + d],
                  __int_as_float(t.z) * x[(long long)t.y * DIM + d]);
    }
}

extern "C" void kernel_launch(void* const* d_in, const int* in_sizes, int n_in,
                              void* d_out, int out_size, void* d_ws, size_t ws_size,
                              hipStream_t stream) {
    const int*   A_rows = (const int*)d_in[0];
    const int*   A_cols = (const int*)d_in[1];
    const float* A_vals = (const float*)d_in[2];
    const float* x      = (const float*)d_in[3];
    float*       out    = (float*)d_out;

    if (d_ws == nullptr || ws_size < WS_NEEDED) {
        // workspace too small: original verified atomic path (needs zeroed out)
        hipMemsetAsync(out, 0, (size_t)out_size * sizeof(float), stream);
        const long long total = (long long)N_EDGES * DIM;
        const int block = 256;
        const long long grid = (total + block - 1) / block;
        spmm_atomic_kernel<<<(dim3)(unsigned)grid, block, 0, stream>>>(
            A_rows, A_cols, A_vals, x, out);
        return;
    }

    char* ws = (char*)d_ws;
    int*  ocount   = (int*)ws;
    int*  counts   = (int*)(ws + OFF_COUNTS);
    int4* overflow = (int4*)(ws + OFF_OVER);
    int2* rowinfo  = (int2*)(ws + OFF_ROWINFO);
    int2* buckets  = (int2*)(ws + OFF_BUCKETS);

    // zero ocount + counters (~51 KB); out fully written by pass 3
    hipMemsetAsync(ws, 0, OFF_OVER, stream);

    const int block = 256;
    spmm_scatter_bucket<<<(N_EDGES + block - 1) / block, block, 0, stream>>>(
        A_rows, A_cols, A_vals, counts, buckets, ocount, overflow);

    spmm_bucket_sort<<<NB, block, 0, stream>>>(counts, buckets, rowinfo);

    spmm_row_gather<<<(N_NODES + 7) / 8, block, 0, stream>>>(
        rowinfo, buckets, x, out);

    spmm_overflow_apply<<<64, block, 0, stream>>>(ocount, overflow, x, out);
}

// Round 6
// 188.588 us; speedup vs baseline: 1.1000x; 1.1000x over previous
//
#include <hip/hip_runtime.h>

// SpMM: out[i,d] = sum_{e: rows[e]==i} vals[e] * x[cols[e], d]
// N=100000 nodes, E=1600000 edges, DIM=32, fp32.
//
// v7: LDS write-combined coarse scatter + per-cbucket counting sort + register gather.
//  Evidence across v2-v6: workspace global stores do NOT combine in L2
//  (8B random stores cost one 64B sector each: r1 99.4MB = 1.6M x 64B;
//  XCC-exact sub selection changed nothing). Coalesced / wave-adjacent
//  writes show exact 1x WRITE. => all scatter writes must be full aligned
//  64B lines issued by one lane back-to-back.
//  v7 scatter: 391 coarse buckets (256 rows each). Per block: 16-entry LDS
//  ring per bucket (ticketed, hole-free; per-round add cap with spill to
//  overflow). Owner thread flushes exactly-8-entry (64B) chunks at 8-granular
//  atomic offsets -> every global write is a full aligned line. Drain pads
//  to 8 with sentinels (x=-1, skipped downstream).
//  sort: per cbucket, 256-row hist (global pass) -> scan -> place real
//  entries into LDS -> linear write-back in place; rowinfo={start,cnt}.
//  gather: v5's register row-gather (writes every out element; no out memset).
//  overflow: rare spills applied by atomic kernel after gather.
//
//  ws layout (~21.5 MB; known ws >= 26.4 MB from v2 run):
//   [0    .. 64)      : ocount
//   [64   .. 2048)    : gcnt, NBC ints
//   [2048 .. 264K)    : overflow, OCAP x int4 {r,c,valbits,_}
//   [264K .. 1.06M)   : rowinfo, N x int2 {start, cnt}
//   [1.06M.. 21.5M)   : region, NBC x CAPC x int2 {(lrow<<17)|col, valbits}

#define N_NODES 100000
#define N_EDGES 1600000
#define DIM 32

#define CBR    256                         // rows per coarse bucket
#define NBC    ((N_NODES + CBR - 1) / CBR) // 391
#define RING   16                          // LDS ring entries per bucket
#define RCAP   9                           // max ring adds per bucket per round (16-7)
#define CHUNK  8                           // flush granularity: 8 x int2 = 64B line
#define CAPC   6528                        // region entries per cbucket (mean ~5786, +9 sigma)
#define OCAP   16384

#define SC_BLOCKS   512
#define SC_THREADS  512
#define EDGES_PER_BLOCK (N_EDGES / SC_BLOCKS)   // 3125 exactly

#define OFF_GCNT    64
#define OFF_OVER    2048
#define OFF_ROWINFO (OFF_OVER + OCAP * 16)
#define OFF_REGION  (((OFF_ROWINFO + N_NODES * 8) + 255) & ~255)
#define WS_NEEDED   ((size_t)OFF_REGION + (size_t)NBC * CAPC * 8)

// ---------- fallback: original verified kernel (thread per (edge,dim)) ----------
__global__ __launch_bounds__(256) void spmm_atomic_kernel(
    const int* __restrict__ rows,
    const int* __restrict__ cols,
    const float* __restrict__ vals,
    const float* __restrict__ x,
    float* __restrict__ out)
{
    const long long idx = (long long)blockIdx.x * blockDim.x + threadIdx.x;
    const long long total = (long long)N_EDGES * DIM;
    if (idx >= total) return;

    const int e = (int)(idx >> 5);
    const int d = (int)(idx & 31);

    const int r   = rows[e];
    const int c   = cols[e];
    const float v = vals[e];

    const float xv = x[(long long)c * DIM + d];
    atomicAdd(&out[(long long)r * DIM + d], v * xv);
}

// ---------- pass 1: write-combined scatter into coarse buckets ----------
__global__ __launch_bounds__(SC_THREADS) void spmm_scatter_wc(
    const int* __restrict__ rows,
    const int* __restrict__ cols,
    const float* __restrict__ vals,
    int* __restrict__ gcnt,          // NBC 8-granular cursors
    int2* __restrict__ region,       // NBC x CAPC
    int* __restrict__ ocount,
    int4* __restrict__ overflow)
{
    __shared__ int2 ring[NBC][RING];   // 50,048 B
    __shared__ int  rtot[NBC];         // accepted tickets (stable during placement)
    __shared__ int  rflu[NBC];         // flushed tickets
    __shared__ int  rrnd[NBC];         // this-round add attempts

    const int tid = threadIdx.x;
    for (int i = tid; i < NBC; i += SC_THREADS) { rtot[i] = 0; rflu[i] = 0; rrnd[i] = 0; }
    __syncthreads();

    const int ebase = blockIdx.x * EDGES_PER_BLOCK;
    const int eend  = ebase + EDGES_PER_BLOCK;    // 512*3125 = 1.6M exactly

    for (int e0 = ebase; e0 < eend; e0 += SC_THREADS) {
        const int e = e0 + tid;
        if (e < eend) {
            const int r  = rows[e];
            const int c  = cols[e];
            const int vb = __float_as_int(vals[e]);
            const int bc = r >> 8;
            const int p  = atomicAdd(&rrnd[bc], 1);
            if (p < RCAP) {
                const int ticket = rtot[bc] + p;    // dense tickets -> no ring holes
                ring[bc][ticket & (RING - 1)] = make_int2(((r & 255) << 17) | c, vb);
            } else {
                // per-round cap exceeded (P ~ 1e-8 per bucket-round on random input)
                const int op = atomicAdd(ocount, 1);
                if (op < OCAP) overflow[op] = make_int4(r, c, vb, 0);
            }
        }
        __syncthreads();

        // flush phase: one owner thread per bucket; only full 64B chunks
        for (int bc = tid; bc < NBC; bc += SC_THREADS) {
            int add = rrnd[bc]; if (add > RCAP) add = RCAP;
            const int tot = rtot[bc] + add;
            rtot[bc] = tot; rrnd[bc] = 0;
            int f = rflu[bc];
            while (tot - f >= CHUNK) {
                const int gpos = atomicAdd(&gcnt[bc], CHUNK);   // 8-granular => 64B aligned
                if (gpos + CHUNK <= CAPC) {
                    int2* dst = region + (size_t)bc * CAPC + gpos;
                    #pragma unroll
                    for (int j = 0; j < CHUNK; ++j) dst[j] = ring[bc][(f + j) & (RING - 1)];
                } else {
                    #pragma unroll
                    for (int j = 0; j < CHUNK; ++j) {
                        const int2 t = ring[bc][(f + j) & (RING - 1)];
                        const int op = atomicAdd(ocount, 1);
                        if (op < OCAP)
                            overflow[op] = make_int4((bc << 8) | (t.x >> 17), t.x & 0x1FFFF, t.y, 0);
                    }
                }
                f += CHUNK;
            }
            rflu[bc] = f;
        }
        __syncthreads();
    }

    // drain: residual 1..7 entries -> one padded 64B chunk (sentinels x=-1)
    for (int bc = tid; bc < NBC; bc += SC_THREADS) {
        const int f = rflu[bc];
        const int k = rtot[bc] - f;        // 0..7
        if (k > 0) {
            const int gpos = atomicAdd(&gcnt[bc], CHUNK);
            if (gpos + CHUNK <= CAPC) {
                int2* dst = region + (size_t)bc * CAPC + gpos;
                #pragma unroll
                for (int j = 0; j < CHUNK; ++j)
                    dst[j] = (j < k) ? ring[bc][(f + j) & (RING - 1)] : make_int2(-1, 0);
            } else {
                for (int j = 0; j < k; ++j) {
                    const int2 t = ring[bc][(f + j) & (RING - 1)];
                    const int op = atomicAdd(ocount, 1);
                    if (op < OCAP)
                        overflow[op] = make_int4((bc << 8) | (t.x >> 17), t.x & 0x1FFFF, t.y, 0);
                }
            }
        }
    }
}

// ---------- pass 2: per-cbucket counting sort by local row (in place) ----------
__global__ __launch_bounds__(256) void spmm_bucket_sort(
    const int* __restrict__ gcnt,
    int2* __restrict__ region,
    int2* __restrict__ rowinfo)
{
    __shared__ int2 srt[CAPC];         // 52.2 KB
    __shared__ int  hist[CBR];
    __shared__ int  startx[CBR];
    __shared__ int  cursor[CBR];

    const int bc  = blockIdx.x;
    const int tid = threadIdx.x;

    int n = gcnt[bc]; if (n > CAPC) n = CAPC;   // written region is exactly [0, min(gcnt,CAPC))
    int2* __restrict__ slice = region + (size_t)bc * CAPC;

    hist[tid] = 0;
    __syncthreads();

    for (int k = tid; k < n; k += 256) {
        const int xv = slice[k].x;
        if (xv >= 0) atomicAdd(&hist[xv >> 17], 1);
    }
    __syncthreads();

    // inclusive Hillis-Steele scan over 256 row counts
    const int h = hist[tid];
    startx[tid] = h;
    __syncthreads();
    for (int off = 1; off < CBR; off <<= 1) {
        int v = startx[tid];
        if (tid >= off) v += startx[tid - off];
        __syncthreads();
        startx[tid] = v;
        __syncthreads();
    }
    const int excl = startx[tid] - h;
    cursor[tid] = excl;
    __syncthreads();

    // place real entries into LDS at sorted position
    for (int k = tid; k < n; k += 256) {
        const int2 e = slice[k];
        if (e.x >= 0) {
            const int p = atomicAdd(&cursor[e.x >> 17], 1);
            srt[p] = make_int2(e.x & 0x1FFFF, e.y);   // store (col, valbits)
        }
    }
    __syncthreads();

    // linear, fully-coalesced write-back over the slice start
    const int m = startx[CBR - 1];
    for (int k = tid; k < m; k += 256) slice[k] = srt[k];

    const int r = bc * CBR + tid;
    if (r < N_NODES) rowinfo[r] = make_int2(bc * CAPC + excl, h);
}

// ---------- pass 3: register-accumulating row gather (v2/v5-proven shape) ----------
__global__ __launch_bounds__(256) void spmm_row_gather(
    const int2* __restrict__ rowinfo,
    const int2* __restrict__ sorted,
    const float* __restrict__ x,
    float* __restrict__ out)
{
    const int d = threadIdx.x & 31;
    const int r = (blockIdx.x << 3) + (threadIdx.x >> 5);
    if (r >= N_NODES) return;

    const int2 ri = rowinfo[r];
    const int2* __restrict__ seg = sorted + ri.x;
    const int cnt = ri.y;

    float acc = 0.f;
    int k = 0;
    for (; k + 3 < cnt; k += 4) {
        const int2 e0 = seg[k + 0];
        const int2 e1 = seg[k + 1];
        const int2 e2 = seg[k + 2];
        const int2 e3 = seg[k + 3];
        const float x0 = x[e0.x * DIM + d];
        const float x1 = x[e1.x * DIM + d];
        const float x2 = x[e2.x * DIM + d];
        const float x3 = x[e3.x * DIM + d];
        acc = fmaf(__int_as_float(e0.y), x0, acc);
        acc = fmaf(__int_as_float(e1.y), x1, acc);
        acc = fmaf(__int_as_float(e2.y), x2, acc);
        acc = fmaf(__int_as_float(e3.y), x3, acc);
    }
    for (; k < cnt; ++k) {
        const int2 e0 = seg[k];
        acc = fmaf(__int_as_float(e0.y), x[e0.x * DIM + d], acc);
    }

    out[r * DIM + d] = acc;   // covers every row (cnt==0 -> 0); no out memset
}

// ---------- pass 4: apply rare overflow edges (normally ~empty) ----------
__global__ __launch_bounds__(256) void spmm_overflow_apply(
    const int* __restrict__ ocount,
    const int4* __restrict__ overflow,
    const float* __restrict__ x,
    float* __restrict__ out)
{
    int n = *ocount;
    if (n > OCAP) n = OCAP;
    const long long total = (long long)n * DIM;
    for (long long idx = (long long)blockIdx.x * blockDim.x + threadIdx.x;
         idx < total; idx += (long long)gridDim.x * blockDim.x) {
        const int e = (int)(idx >> 5);
        const int d = (int)(idx & 31);
        const int4 t = overflow[e];
        atomicAdd(&out[(long long)t.x * DIM + d],
                  __int_as_float(t.z) * x[(long long)t.y * DIM + d]);
    }
}

extern "C" void kernel_launch(void* const* d_in, const int* in_sizes, int n_in,
                              void* d_out, int out_size, void* d_ws, size_t ws_size,
                              hipStream_t stream) {
    const int*   A_rows = (const int*)d_in[0];
    const int*   A_cols = (const int*)d_in[1];
    const float* A_vals = (const float*)d_in[2];
    const float* x      = (const float*)d_in[3];
    float*       out    = (float*)d_out;

    if (d_ws == nullptr || ws_size < WS_NEEDED) {
        // workspace too small: original verified atomic path (needs zeroed out)
        hipMemsetAsync(out, 0, (size_t)out_size * sizeof(float), stream);
        const long long total = (long long)N_EDGES * DIM;
        const int block = 256;
        const long long grid = (total + block - 1) / block;
        spmm_atomic_kernel<<<(dim3)(unsigned)grid, block, 0, stream>>>(
            A_rows, A_cols, A_vals, x, out);
        return;
    }

    char* ws = (char*)d_ws;
    int*  ocount   = (int*)ws;
    int*  gcnt     = (int*)(ws + OFF_GCNT);
    int4* overflow = (int4*)(ws + OFF_OVER);
    int2* rowinfo  = (int2*)(ws + OFF_ROWINFO);
    int2* region   = (int2*)(ws + OFF_REGION);

    // zero ocount + gcnt only (2 KB); out fully written by pass 3
    hipMemsetAsync(ws, 0, OFF_OVER, stream);

    spmm_scatter_wc<<<SC_BLOCKS, SC_THREADS, 0, stream>>>(
        A_rows, A_cols, A_vals, gcnt, region, ocount, overflow);

    spmm_bucket_sort<<<NBC, 256, 0, stream>>>(gcnt, region, rowinfo);

    spmm_row_gather<<<(N_NODES + 7) / 8, 256, 0, stream>>>(
        rowinfo, region, x, out);

    spmm_overflow_apply<<<64, 256, 0, stream>>>(ocount, overflow, x, out);
}

// Round 7
// 159.587 us; speedup vs baseline: 1.2999x; 1.1817x over previous
//
#include <hip/hip_runtime.h>

// SpMM: out[i,d] = sum_{e: rows[e]==i} vals[e] * x[cols[e], d]
// N=100000 nodes, E=1600000 edges, DIM=32, fp32.
//
// v8: single-pass register-staged WC scatter + line-padded cursors.
//  v7 post-mortem: WRITE_SIZE fixed (20.8MB) but dur 56us with VALUBusy 3% ->
//  stall is ~200K returning global atomicAdds on gcnt[] packed 16/cache-line
//  (25 lines; ~8K line-serialized RMWs x ~7ns = ~55us). Evidence: v5 (64B-padded
//  counters) scatter 71us -> v6 (packed) 83us regression.
//  v8 scatter: one round per block. 3200 edges staged in REGISTERS, LDS
//  391-bucket histogram -> scan -> ONE 8-granular global reservation per
//  (block,bucket) on 64B-PADDED cursors (391 parallel atomics, off serial
//  loops) -> place into LDS staging (bucket-contiguous) -> flush full 64B
//  lines (sentinel pad, one-lane bursts = v7-proven write-combining).
//  LDS 34KB -> 4 blocks/CU. sort/gather/overflow unchanged from v7 shape.
//
//  ws layout (~21.9 MB; known ws >= 26.0 MB from v2 run):
//   [0     .. 64)     : ocount
//   [64    .. 25088)  : gcnt, NBC x 64B-padded int
//   [25088 .. 287K)   : overflow, OCAP x int4 {r,c,valbits,_}
//   [287K  .. 1.09M)  : rowinfo, N x int2 {start, cnt}
//   [1.09M .. 21.9M)  : region, NBC x CAPC x int2 {(lrow<<17)|col, valbits}

#define N_NODES 100000
#define N_EDGES 1600000
#define DIM 32

#define CBR    256                         // rows per coarse bucket
#define NBC    ((N_NODES + CBR - 1) / CBR) // 391
#define CHUNK  8                           // 8 x int2 = 64B line
#define CAPC   6656                        // entries/bucket (mean ~5992 incl pad, +8 sigma)
#define OCAP   16384

#define SC_BLOCKS   500
#define SC_THREADS  512
#define EPB         3200                   // edges per block: 500*3200 = 1.6M exactly
#define EPT         7                      // ceil(3200/512)

#define OFF_GCNT    64
#define OFF_OVER    (OFF_GCNT + NBC * 64)                     // 25088
#define OFF_ROWINFO (OFF_OVER + OCAP * 16)
#define OFF_REGION  (((OFF_ROWINFO + N_NODES * 8) + 255) & ~255)
#define WS_NEEDED   ((size_t)OFF_REGION + (size_t)NBC * CAPC * 8)

// ---------- fallback: original verified kernel (thread per (edge,dim)) ----------
__global__ __launch_bounds__(256) void spmm_atomic_kernel(
    const int* __restrict__ rows,
    const int* __restrict__ cols,
    const float* __restrict__ vals,
    const float* __restrict__ x,
    float* __restrict__ out)
{
    const long long idx = (long long)blockIdx.x * blockDim.x + threadIdx.x;
    const long long total = (long long)N_EDGES * DIM;
    if (idx >= total) return;

    const int e = (int)(idx >> 5);
    const int d = (int)(idx & 31);

    const int r   = rows[e];
    const int c   = cols[e];
    const float v = vals[e];

    const float xv = x[(long long)c * DIM + d];
    atomicAdd(&out[(long long)r * DIM + d], v * xv);
}

// ---------- pass 1: single-round register-staged WC scatter ----------
__global__ __launch_bounds__(SC_THREADS) void spmm_scatter_ws(
    const int* __restrict__ rows,
    const int* __restrict__ cols,
    const float* __restrict__ vals,
    int* __restrict__ gcnt,          // NBC cursors, 64B-padded (index *16)
    int2* __restrict__ region,       // NBC x CAPC
    int* __restrict__ ocount,
    int4* __restrict__ overflow)
{
    __shared__ int2 stage[EPB];      // 25.6 KB, bucket-contiguous staging
    __shared__ int  hist[NBC];
    __shared__ int  lstart[NBC];     // LDS segment start per bucket
    __shared__ int  cursor[NBC];
    __shared__ int  gbase[NBC];      // global reservation per bucket
    __shared__ int  scanb[SC_THREADS];

    const int tid   = threadIdx.x;
    const int ebase = blockIdx.x * EPB;

    for (int i = tid; i < NBC; i += SC_THREADS) hist[i] = 0;
    __syncthreads();

    // load edges into registers (compile-time indices -> stays in VGPRs), histogram
    int en_x[EPT], en_y[EPT], eb[EPT];
    #pragma unroll
    for (int i = 0; i < EPT; ++i) {
        const int o = i * SC_THREADS + tid;
        if (o < EPB) {
            const int e = ebase + o;
            const int r = rows[e];
            eb[i]   = r >> 8;
            en_x[i] = ((r & 255) << 17) | cols[e];
            en_y[i] = __float_as_int(vals[e]);
            atomicAdd(&hist[eb[i]], 1);
        } else {
            eb[i] = -1; en_x[i] = 0; en_y[i] = 0;
        }
    }
    __syncthreads();

    // exclusive scan of hist over padded-512 (Hillis-Steele)
    const int myh = (tid < NBC) ? hist[tid] : 0;
    scanb[tid] = myh;
    __syncthreads();
    for (int off = 1; off < SC_THREADS; off <<= 1) {
        int t = scanb[tid];
        if (tid >= off) t += scanb[tid - off];
        __syncthreads();
        scanb[tid] = t;
        __syncthreads();
    }
    if (tid < NBC) {
        const int excl = scanb[tid] - myh;
        lstart[tid] = excl;
        cursor[tid] = excl;
        const int pad = (myh + 7) & ~7;
        // ONE reservation per (block,bucket); 64B-padded counter -> no line contention
        gbase[tid] = pad ? atomicAdd(&gcnt[tid * 16], pad) : 0;
    }
    __syncthreads();

    // place register-staged entries into bucket-contiguous LDS
    #pragma unroll
    for (int i = 0; i < EPT; ++i) {
        if (eb[i] >= 0) {
            const int p = atomicAdd(&cursor[eb[i]], 1);
            stage[p] = make_int2(en_x[i], en_y[i]);
        }
    }
    __syncthreads();

    // flush: full 64B lines only (sentinel pad), one-lane bursts (v7-proven WC)
    for (int bc = tid; bc < NBC; bc += SC_THREADS) {
        const int n   = hist[bc];
        const int ls  = lstart[bc];
        const int gb  = gbase[bc];
        const int nch = (n + 7) >> 3;
        for (int jch = 0; jch < nch; ++jch) {
            const int gpos = gb + jch * CHUNK;
            if (gpos + CHUNK <= CAPC) {
                int2* dst = region + (size_t)bc * CAPC + gpos;
                #pragma unroll
                for (int j = 0; j < CHUNK; ++j) {
                    const int k = jch * CHUNK + j;
                    dst[j] = (k < n) ? stage[ls + k] : make_int2(-1, 0);
                }
            } else {
                // capacity overflow (rare): spill real entries
                for (int j = 0; j < CHUNK; ++j) {
                    const int k = jch * CHUNK + j;
                    if (k < n) {
                        const int2 t = stage[ls + k];
                        const int op = atomicAdd(ocount, 1);
                        if (op < OCAP)
                            overflow[op] = make_int4((bc << 8) | (t.x >> 17),
                                                     t.x & 0x1FFFF, t.y, 0);
                    }
                }
            }
        }
    }
}

// ---------- pass 2: per-cbucket counting sort by local row (in place) ----------
__global__ __launch_bounds__(256) void spmm_bucket_sort(
    const int* __restrict__ gcnt,
    int2* __restrict__ region,
    int2* __restrict__ rowinfo)
{
    __shared__ int2 srt[CAPC];         // 53.2 KB
    __shared__ int  hist[CBR];
    __shared__ int  startx[CBR];
    __shared__ int  cursor[CBR];

    const int bc  = blockIdx.x;
    const int tid = threadIdx.x;

    int n = gcnt[bc * 16]; if (n > CAPC) n = CAPC;   // written region = [0, min(gcnt,CAPC))
    int2* __restrict__ slice = region + (size_t)bc * CAPC;

    hist[tid] = 0;
    __syncthreads();

    for (int k = tid; k < n; k += 256) {
        const int xv = slice[k].x;
        if (xv >= 0) atomicAdd(&hist[xv >> 17], 1);
    }
    __syncthreads();

    // inclusive Hillis-Steele scan over 256 row counts
    const int h = hist[tid];
    startx[tid] = h;
    __syncthreads();
    for (int off = 1; off < CBR; off <<= 1) {
        int v = startx[tid];
        if (tid >= off) v += startx[tid - off];
        __syncthreads();
        startx[tid] = v;
        __syncthreads();
    }
    const int excl = startx[tid] - h;
    cursor[tid] = excl;
    __syncthreads();

    // place real entries into LDS at sorted position
    for (int k = tid; k < n; k += 256) {
        const int2 e = slice[k];
        if (e.x >= 0) {
            const int p = atomicAdd(&cursor[e.x >> 17], 1);
            srt[p] = make_int2(e.x & 0x1FFFF, e.y);   // store (col, valbits)
        }
    }
    __syncthreads();

    // linear, fully-coalesced write-back over the slice start
    const int m = startx[CBR - 1];
    for (int k = tid; k < m; k += 256) slice[k] = srt[k];

    const int r = bc * CBR + tid;
    if (r < N_NODES) rowinfo[r] = make_int2(bc * CAPC + excl, h);
}

// ---------- pass 3: register-accumulating row gather (v2/v5-proven shape) ----------
__global__ __launch_bounds__(256) void spmm_row_gather(
    const int2* __restrict__ rowinfo,
    const int2* __restrict__ sorted,
    const float* __restrict__ x,
    float* __restrict__ out)
{
    const int d = threadIdx.x & 31;
    const int r = (blockIdx.x << 3) + (threadIdx.x >> 5);
    if (r >= N_NODES) return;

    const int2 ri = rowinfo[r];
    const int2* __restrict__ seg = sorted + ri.x;
    const int cnt = ri.y;

    float acc = 0.f;
    int k = 0;
    for (; k + 3 < cnt; k += 4) {
        const int2 e0 = seg[k + 0];
        const int2 e1 = seg[k + 1];
        const int2 e2 = seg[k + 2];
        const int2 e3 = seg[k + 3];
        const float x0 = x[e0.x * DIM + d];
        const float x1 = x[e1.x * DIM + d];
        const float x2 = x[e2.x * DIM + d];
        const float x3 = x[e3.x * DIM + d];
        acc = fmaf(__int_as_float(e0.y), x0, acc);
        acc = fmaf(__int_as_float(e1.y), x1, acc);
        acc = fmaf(__int_as_float(e2.y), x2, acc);
        acc = fmaf(__int_as_float(e3.y), x3, acc);
    }
    for (; k < cnt; ++k) {
        const int2 e0 = seg[k];
        acc = fmaf(__int_as_float(e0.y), x[e0.x * DIM + d], acc);
    }

    out[r * DIM + d] = acc;   // covers every row (cnt==0 -> 0); no out memset
}

// ---------- pass 4: apply rare overflow edges (normally ~empty) ----------
__global__ __launch_bounds__(256) void spmm_overflow_apply(
    const int* __restrict__ ocount,
    const int4* __restrict__ overflow,
    const float* __restrict__ x,
    float* __restrict__ out)
{
    int n = *ocount;
    if (n > OCAP) n = OCAP;
    const long long total = (long long)n * DIM;
    for (long long idx = (long long)blockIdx.x * blockDim.x + threadIdx.x;
         idx < total; idx += (long long)gridDim.x * blockDim.x) {
        const int e = (int)(idx >> 5);
        const int d = (int)(idx & 31);
        const int4 t = overflow[e];
        atomicAdd(&out[(long long)t.x * DIM + d],
                  __int_as_float(t.z) * x[(long long)t.y * DIM + d]);
    }
}

extern "C" void kernel_launch(void* const* d_in, const int* in_sizes, int n_in,
                              void* d_out, int out_size, void* d_ws, size_t ws_size,
                              hipStream_t stream) {
    const int*   A_rows = (const int*)d_in[0];
    const int*   A_cols = (const int*)d_in[1];
    const float* A_vals = (const float*)d_in[2];
    const float* x      = (const float*)d_in[3];
    float*       out    = (float*)d_out;

    if (d_ws == nullptr || ws_size < WS_NEEDED) {
        // workspace too small: original verified atomic path (needs zeroed out)
        hipMemsetAsync(out, 0, (size_t)out_size * sizeof(float), stream);
        const long long total = (long long)N_EDGES * DIM;
        const int block = 256;
        const long long grid = (total + block - 1) / block;
        spmm_atomic_kernel<<<(dim3)(unsigned)grid, block, 0, stream>>>(
            A_rows, A_cols, A_vals, x, out);
        return;
    }

    char* ws = (char*)d_ws;
    int*  ocount   = (int*)ws;
    int*  gcnt     = (int*)(ws + OFF_GCNT);
    int4* overflow = (int4*)(ws + OFF_OVER);
    int2* rowinfo  = (int2*)(ws + OFF_ROWINFO);
    int2* region   = (int2*)(ws + OFF_REGION);

    // zero ocount + padded gcnt (25 KB); out fully written by pass 3
    hipMemsetAsync(ws, 0, OFF_OVER, stream);

    spmm_scatter_ws<<<SC_BLOCKS, SC_THREADS, 0, stream>>>(
        A_rows, A_cols, A_vals, gcnt, region, ocount, overflow);

    spmm_bucket_sort<<<NBC, 256, 0, stream>>>(gcnt, region, rowinfo);

    spmm_row_gather<<<(N_NODES + 7) / 8, 256, 0, stream>>>(
        rowinfo, region, x, out);

    spmm_overflow_apply<<<64, 256, 0, stream>>>(ocount, overflow, x, out);
}

// Round 8
// 153.473 us; speedup vs baseline: 1.3517x; 1.0398x over previous
//
#include <hip/hip_runtime.h>

// SpMM: out[i,d] = sum_{e: rows[e]==i} vals[e] * x[cols[e], d]
// N=100000 nodes, E=1600000 edges, DIM=32, fp32.
//
// v9: v8 scatter + 4B-quantized sorted entries + wave-per-row float4 gather.
//  v8 post-mortem: scatter fixed (<43us, out of top-5). Gather = 42.9us,
//  FETCH 82MB (structural: each XCD needs ~88% of x's lines once), HBM 28%,
//  VALU 19% -> latency-bound, not BW-bound. v9 raises MLP: one 64-lane wave
//  per row, 8 entry-slots x 8 float4 dim-quarters, unroll-2 -> 16 x-lines
//  in flight per wave (vs 4 scalar chains before); 3 shfl_xor steps reduce.
//  Sorted entries shrink 8B -> 4B: after sort lrow is implicit in rowinfo,
//  so entry = (q15<<17)|col with val quantized to 15-bit fixed point in [0,1]
//  (error <= deg * 2^-16 * |x| ~ 2e-3 << 0.03125 tol). Sort LDS 53->27KB,
//  writeback 12.8->6.4MB, gather entry reads halved. Overflow stays fp32.
//
//  ws layout (~21.9 MB):
//   [0     .. 64)     : ocount
//   [64    .. 25088)  : gcnt, NBC x 64B-padded int
//   [25088 .. 287K)   : overflow, OCAP x int4 {r,c,valbits,_}
//   [287K  .. 1.09M)  : rowinfo, N x int2 {startInt, cnt}
//   [1.09M .. 21.9M)  : region, NBC x CAPC x int2 (scatter); sorted ints in
//                       the first half of each slice after pass 2

#define N_NODES 100000
#define N_EDGES 1600000
#define DIM 32

#define CBR    256                         // rows per coarse bucket
#define NBC    ((N_NODES + CBR - 1) / CBR) // 391
#define CHUNK  8                           // 8 x int2 = 64B line
#define CAPC   6656                        // entries/bucket (mean ~5992 incl pad, +8 sigma)
#define OCAP   16384

#define SC_BLOCKS   500
#define SC_THREADS  512
#define EPB         3200                   // edges per block: 500*3200 = 1.6M exactly
#define EPT         7                      // ceil(3200/512)

#define OFF_GCNT    64
#define OFF_OVER    (OFF_GCNT + NBC * 64)                     // 25088
#define OFF_ROWINFO (OFF_OVER + OCAP * 16)
#define OFF_REGION  (((OFF_ROWINFO + N_NODES * 8) + 255) & ~255)
#define WS_NEEDED   ((size_t)OFF_REGION + (size_t)NBC * CAPC * 8)

// ---------- fallback: original verified kernel (thread per (edge,dim)) ----------
__global__ __launch_bounds__(256) void spmm_atomic_kernel(
    const int* __restrict__ rows,
    const int* __restrict__ cols,
    const float* __restrict__ vals,
    const float* __restrict__ x,
    float* __restrict__ out)
{
    const long long idx = (long long)blockIdx.x * blockDim.x + threadIdx.x;
    const long long total = (long long)N_EDGES * DIM;
    if (idx >= total) return;

    const int e = (int)(idx >> 5);
    const int d = (int)(idx & 31);

    const int r   = rows[e];
    const int c   = cols[e];
    const float v = vals[e];

    const float xv = x[(long long)c * DIM + d];
    atomicAdd(&out[(long long)r * DIM + d], v * xv);
}

// ---------- pass 1: single-round register-staged WC scatter (v8-proven) ----------
__global__ __launch_bounds__(SC_THREADS) void spmm_scatter_ws(
    const int* __restrict__ rows,
    const int* __restrict__ cols,
    const float* __restrict__ vals,
    int* __restrict__ gcnt,          // NBC cursors, 64B-padded (index *16)
    int2* __restrict__ region,       // NBC x CAPC
    int* __restrict__ ocount,
    int4* __restrict__ overflow)
{
    __shared__ int2 stage[EPB];      // 25.6 KB, bucket-contiguous staging
    __shared__ int  hist[NBC];
    __shared__ int  lstart[NBC];     // LDS segment start per bucket
    __shared__ int  cursor[NBC];
    __shared__ int  gbase[NBC];      // global reservation per bucket
    __shared__ int  scanb[SC_THREADS];

    const int tid   = threadIdx.x;
    const int ebase = blockIdx.x * EPB;

    for (int i = tid; i < NBC; i += SC_THREADS) hist[i] = 0;
    __syncthreads();

    // load edges into registers (compile-time indices -> stays in VGPRs), histogram
    int en_x[EPT], en_y[EPT], eb[EPT];
    #pragma unroll
    for (int i = 0; i < EPT; ++i) {
        const int o = i * SC_THREADS + tid;
        if (o < EPB) {
            const int e = ebase + o;
            const int r = rows[e];
            eb[i]   = r >> 8;
            en_x[i] = ((r & 255) << 17) | cols[e];
            en_y[i] = __float_as_int(vals[e]);
            atomicAdd(&hist[eb[i]], 1);
        } else {
            eb[i] = -1; en_x[i] = 0; en_y[i] = 0;
        }
    }
    __syncthreads();

    // exclusive scan of hist over padded-512 (Hillis-Steele)
    const int myh = (tid < NBC) ? hist[tid] : 0;
    scanb[tid] = myh;
    __syncthreads();
    for (int off = 1; off < SC_THREADS; off <<= 1) {
        int t = scanb[tid];
        if (tid >= off) t += scanb[tid - off];
        __syncthreads();
        scanb[tid] = t;
        __syncthreads();
    }
    if (tid < NBC) {
        const int excl = scanb[tid] - myh;
        lstart[tid] = excl;
        cursor[tid] = excl;
        const int pad = (myh + 7) & ~7;
        // ONE reservation per (block,bucket); 64B-padded counter -> no line contention
        gbase[tid] = pad ? atomicAdd(&gcnt[tid * 16], pad) : 0;
    }
    __syncthreads();

    // place register-staged entries into bucket-contiguous LDS
    #pragma unroll
    for (int i = 0; i < EPT; ++i) {
        if (eb[i] >= 0) {
            const int p = atomicAdd(&cursor[eb[i]], 1);
            stage[p] = make_int2(en_x[i], en_y[i]);
        }
    }
    __syncthreads();

    // flush: full 64B lines only (sentinel pad), one-lane bursts (v7-proven WC)
    for (int bc = tid; bc < NBC; bc += SC_THREADS) {
        const int n   = hist[bc];
        const int ls  = lstart[bc];
        const int gb  = gbase[bc];
        const int nch = (n + 7) >> 3;
        for (int jch = 0; jch < nch; ++jch) {
            const int gpos = gb + jch * CHUNK;
            if (gpos + CHUNK <= CAPC) {
                int2* dst = region + (size_t)bc * CAPC + gpos;
                #pragma unroll
                for (int j = 0; j < CHUNK; ++j) {
                    const int k = jch * CHUNK + j;
                    dst[j] = (k < n) ? stage[ls + k] : make_int2(-1, 0);
                }
            } else {
                // capacity overflow (rare): spill real entries
                for (int j = 0; j < CHUNK; ++j) {
                    const int k = jch * CHUNK + j;
                    if (k < n) {
                        const int2 t = stage[ls + k];
                        const int op = atomicAdd(ocount, 1);
                        if (op < OCAP)
                            overflow[op] = make_int4((bc << 8) | (t.x >> 17),
                                                     t.x & 0x1FFFF, t.y, 0);
                    }
                }
            }
        }
    }
}

// ---------- pass 2: per-cbucket counting sort -> 4B quantized entries ----------
__global__ __launch_bounds__(256) void spmm_bucket_sort(
    const int* __restrict__ gcnt,
    int2* __restrict__ region,
    int2* __restrict__ rowinfo)
{
    __shared__ int srt[CAPC];          // 26.6 KB (packed 4B entries)
    __shared__ int hist[CBR];
    __shared__ int startx[CBR];
    __shared__ int cursor[CBR];

    const int bc  = blockIdx.x;
    const int tid = threadIdx.x;

    int n = gcnt[bc * 16]; if (n > CAPC) n = CAPC;   // written region = [0, min(gcnt,CAPC))
    int2* __restrict__ slice = region + (size_t)bc * CAPC;

    hist[tid] = 0;
    __syncthreads();

    for (int k = tid; k < n; k += 256) {
        const int xv = slice[k].x;
        if (xv >= 0) atomicAdd(&hist[xv >> 17], 1);
    }
    __syncthreads();

    // inclusive Hillis-Steele scan over 256 row counts
    const int h = hist[tid];
    startx[tid] = h;
    __syncthreads();
    for (int off = 1; off < CBR; off <<= 1) {
        int v = startx[tid];
        if (tid >= off) v += startx[tid - off];
        __syncthreads();
        startx[tid] = v;
        __syncthreads();
    }
    const int excl = startx[tid] - h;
    cursor[tid] = excl;
    __syncthreads();

    // place real entries at sorted LDS position, quantizing val to 15-bit [0,1]
    for (int k = tid; k < n; k += 256) {
        const int2 e = slice[k];
        if (e.x >= 0) {
            const int p = atomicAdd(&cursor[e.x >> 17], 1);
            int q = (int)(__int_as_float(e.y) * 32768.f + 0.5f);
            if (q > 32767) q = 32767;
            srt[p] = (q << 17) | (e.x & 0x1FFFF);    // (q15 << 17) | col17
        }
    }
    __syncthreads();

    // linear, fully-coalesced 4B write-back over the slice start
    int* __restrict__ islice = (int*)slice;
    const int m = startx[CBR - 1];
    for (int k = tid; k < m; k += 256) islice[k] = srt[k];

    const int r = bc * CBR + tid;
    if (r < N_NODES)
        rowinfo[r] = make_int2(bc * (CAPC * 2) + excl, h);   // start in INT units
}

// ---------- pass 3: wave-per-row gather, 8 entries x float4 in parallel ----------
__global__ __launch_bounds__(256) void spmm_row_gather(
    const int2* __restrict__ rowinfo,
    const int* __restrict__ sortedi,
    const float* __restrict__ x,
    float* __restrict__ out)
{
    const int lane = threadIdx.x & 63;
    const int r    = blockIdx.x * 4 + (threadIdx.x >> 6);   // 4 waves/block
    if (r >= N_NODES) return;

    const int2 ri = rowinfo[r];
    const int* __restrict__ seg = sortedi + ri.x;
    const int cnt = ri.y;

    const int eg = lane >> 3;   // entry-slot 0..7
    const int d4 = lane & 7;    // float4 quarter of the row

    float4 acc = make_float4(0.f, 0.f, 0.f, 0.f);
    for (int k0 = 0; k0 < cnt; k0 += 16) {
        const int ka = k0 + eg;
        const int kb = ka + 8;
        // sentinel 0: col 0, q 0 -> v=0 (harmless in-bounds x[0] read)
        const int ea = (ka < cnt) ? seg[ka] : 0;
        const int eb = (kb < cnt) ? seg[kb] : 0;
        const float va = (float)((unsigned)ea >> 17) * (1.f / 32768.f);
        const float vb = (float)((unsigned)eb >> 17) * (1.f / 32768.f);
        const float4 xa = *(const float4*)&x[(ea & 0x1FFFF) * DIM + d4 * 4];
        const float4 xb = *(const float4*)&x[(eb & 0x1FFFF) * DIM + d4 * 4];
        acc.x = fmaf(va, xa.x, acc.x);  acc.y = fmaf(va, xa.y, acc.y);
        acc.z = fmaf(va, xa.z, acc.z);  acc.w = fmaf(va, xa.w, acc.w);
        acc.x = fmaf(vb, xb.x, acc.x);  acc.y = fmaf(vb, xb.y, acc.y);
        acc.z = fmaf(vb, xb.z, acc.z);  acc.w = fmaf(vb, xb.w, acc.w);
    }

    // reduce the 8 entry-slots (xor 8,16,32 across the 64-lane wave)
    #pragma unroll
    for (int m = 8; m < 64; m <<= 1) {
        acc.x += __shfl_xor(acc.x, m, 64);
        acc.y += __shfl_xor(acc.y, m, 64);
        acc.z += __shfl_xor(acc.z, m, 64);
        acc.w += __shfl_xor(acc.w, m, 64);
    }
    if (eg == 0)
        *(float4*)&out[r * DIM + d4 * 4] = acc;   // covers every row; no out memset
}

// ---------- pass 4: apply rare overflow edges (normally ~empty) ----------
__global__ __launch_bounds__(256) void spmm_overflow_apply(
    const int* __restrict__ ocount,
    const int4* __restrict__ overflow,
    const float* __restrict__ x,
    float* __restrict__ out)
{
    int n = *ocount;
    if (n > OCAP) n = OCAP;
    const long long total = (long long)n * DIM;
    for (long long idx = (long long)blockIdx.x * blockDim.x + threadIdx.x;
         idx < total; idx += (long long)gridDim.x * blockDim.x) {
        const int e = (int)(idx >> 5);
        const int d = (int)(idx & 31);
        const int4 t = overflow[e];
        atomicAdd(&out[(long long)t.x * DIM + d],
                  __int_as_float(t.z) * x[(long long)t.y * DIM + d]);
    }
}

extern "C" void kernel_launch(void* const* d_in, const int* in_sizes, int n_in,
                              void* d_out, int out_size, void* d_ws, size_t ws_size,
                              hipStream_t stream) {
    const int*   A_rows = (const int*)d_in[0];
    const int*   A_cols = (const int*)d_in[1];
    const float* A_vals = (const float*)d_in[2];
    const float* x      = (const float*)d_in[3];
    float*       out    = (float*)d_out;

    if (d_ws == nullptr || ws_size < WS_NEEDED) {
        // workspace too small: original verified atomic path (needs zeroed out)
        hipMemsetAsync(out, 0, (size_t)out_size * sizeof(float), stream);
        const long long total = (long long)N_EDGES * DIM;
        const int block = 256;
        const long long grid = (total + block - 1) / block;
        spmm_atomic_kernel<<<(dim3)(unsigned)grid, block, 0, stream>>>(
            A_rows, A_cols, A_vals, x, out);
        return;
    }

    char* ws = (char*)d_ws;
    int*  ocount   = (int*)ws;
    int*  gcnt     = (int*)(ws + OFF_GCNT);
    int4* overflow = (int4*)(ws + OFF_OVER);
    int2* rowinfo  = (int2*)(ws + OFF_ROWINFO);
    int2* region   = (int2*)(ws + OFF_REGION);

    // zero ocount + padded gcnt (25 KB); out fully written by pass 3
    hipMemsetAsync(ws, 0, OFF_OVER, stream);

    spmm_scatter_ws<<<SC_BLOCKS, SC_THREADS, 0, stream>>>(
        A_rows, A_cols, A_vals, gcnt, region, ocount, overflow);

    spmm_bucket_sort<<<NBC, 256, 0, stream>>>(gcnt, region, rowinfo);

    spmm_row_gather<<<(N_NODES + 3) / 4, 256, 0, stream>>>(
        rowinfo, (const int*)region, x, out);

    spmm_overflow_apply<<<64, 256, 0, stream>>>(ocount, overflow, x, out);
}

// Round 9
// 136.916 us; speedup vs baseline: 1.5151x; 1.1209x over previous
//
#include <hip/hip_runtime.h>

// SpMM: out[i,d] = sum_{e: rows[e]==i} vals[e] * x[cols[e], d]
// N=100000 nodes, E=1600000 edges, DIM=32, fp32.
//
// v10: v8 scatter + FUSED sort+gather (one block per bucket).
//  v9 post-mortem: all our kernels < 43us (below harness fill dispatches);
//  remaining cost ~85us across 4 kernels. The sort->gather handoff paid
//  6.4MB write + 6.9MB read + 1.6MB rowinfo + a launch, and the gather's
//  per-row chain was rowinfo->seg->x (3 serial global round trips).
//  v10 fuses: per-bucket block sorts entries into LDS (full int2, NO
//  quantization -> absmax back to fp32-ordering level), then the same
//  block's 16 waves gather straight from LDS (chain = x only, 16 x-lines
//  in flight per wave, 8 waves/SIMD resident).
//    pass1 scatter (v8-proven WC)   pass2 fused sort+gather -> out
//    pass3 rare overflow apply
//
//  ws layout (~21.1 MB):
//   [0     .. 64)     : ocount
//   [64    .. 25088)  : gcnt, NBC x 64B-padded int
//   [25088 .. 287K)   : overflow, OCAP x int4 {r,c,valbits,_}
//   [~287K .. ~21.1M) : region, NBC x CAPC x int2 {(lrow<<17)|col, valbits}

#define N_NODES 100000
#define N_EDGES 1600000
#define DIM 32

#define CBR    256                         // rows per coarse bucket
#define NBC    ((N_NODES + CBR - 1) / CBR) // 391
#define CHUNK  8                           // 8 x int2 = 64B line
#define CAPC   6656                        // entries/bucket (mean ~5751 incl pad, +8 sigma)
#define OCAP   16384

#define SC_BLOCKS   500
#define SC_THREADS  512
#define EPB         3200                   // edges per block: 500*3200 = 1.6M exactly
#define EPT         7                      // ceil(3200/512)

#define OFF_GCNT    64
#define OFF_OVER    (OFF_GCNT + NBC * 64)                     // 25088
#define OFF_REGION  (((OFF_OVER + OCAP * 16) + 255) & ~255)
#define WS_NEEDED   ((size_t)OFF_REGION + (size_t)NBC * CAPC * 8)

// ---------- fallback: original verified kernel (thread per (edge,dim)) ----------
__global__ __launch_bounds__(256) void spmm_atomic_kernel(
    const int* __restrict__ rows,
    const int* __restrict__ cols,
    const float* __restrict__ vals,
    const float* __restrict__ x,
    float* __restrict__ out)
{
    const long long idx = (long long)blockIdx.x * blockDim.x + threadIdx.x;
    const long long total = (long long)N_EDGES * DIM;
    if (idx >= total) return;

    const int e = (int)(idx >> 5);
    const int d = (int)(idx & 31);

    const int r   = rows[e];
    const int c   = cols[e];
    const float v = vals[e];

    const float xv = x[(long long)c * DIM + d];
    atomicAdd(&out[(long long)r * DIM + d], v * xv);
}

// ---------- pass 1: single-round register-staged WC scatter (v8-proven) ----------
__global__ __launch_bounds__(SC_THREADS) void spmm_scatter_ws(
    const int* __restrict__ rows,
    const int* __restrict__ cols,
    const float* __restrict__ vals,
    int* __restrict__ gcnt,          // NBC cursors, 64B-padded (index *16)
    int2* __restrict__ region,       // NBC x CAPC
    int* __restrict__ ocount,
    int4* __restrict__ overflow)
{
    __shared__ int2 stage[EPB];      // 25.6 KB, bucket-contiguous staging
    __shared__ int  hist[NBC];
    __shared__ int  lstart[NBC];     // LDS segment start per bucket
    __shared__ int  cursor[NBC];
    __shared__ int  gbase[NBC];      // global reservation per bucket
    __shared__ int  scanb[SC_THREADS];

    const int tid   = threadIdx.x;
    const int ebase = blockIdx.x * EPB;

    for (int i = tid; i < NBC; i += SC_THREADS) hist[i] = 0;
    __syncthreads();

    // load edges into registers (compile-time indices -> stays in VGPRs), histogram
    int en_x[EPT], en_y[EPT], eb[EPT];
    #pragma unroll
    for (int i = 0; i < EPT; ++i) {
        const int o = i * SC_THREADS + tid;
        if (o < EPB) {
            const int e = ebase + o;
            const int r = rows[e];
            eb[i]   = r >> 8;
            en_x[i] = ((r & 255) << 17) | cols[e];
            en_y[i] = __float_as_int(vals[e]);
            atomicAdd(&hist[eb[i]], 1);
        } else {
            eb[i] = -1; en_x[i] = 0; en_y[i] = 0;
        }
    }
    __syncthreads();

    // exclusive scan of hist over padded-512 (Hillis-Steele)
    const int myh = (tid < NBC) ? hist[tid] : 0;
    scanb[tid] = myh;
    __syncthreads();
    for (int off = 1; off < SC_THREADS; off <<= 1) {
        int t = scanb[tid];
        if (tid >= off) t += scanb[tid - off];
        __syncthreads();
        scanb[tid] = t;
        __syncthreads();
    }
    if (tid < NBC) {
        const int excl = scanb[tid] - myh;
        lstart[tid] = excl;
        cursor[tid] = excl;
        const int pad = (myh + 7) & ~7;
        // ONE reservation per (block,bucket); 64B-padded counter -> no line contention
        gbase[tid] = pad ? atomicAdd(&gcnt[tid * 16], pad) : 0;
    }
    __syncthreads();

    // place register-staged entries into bucket-contiguous LDS
    #pragma unroll
    for (int i = 0; i < EPT; ++i) {
        if (eb[i] >= 0) {
            const int p = atomicAdd(&cursor[eb[i]], 1);
            stage[p] = make_int2(en_x[i], en_y[i]);
        }
    }
    __syncthreads();

    // flush: full 64B lines only (sentinel pad), one-lane bursts (v7-proven WC)
    for (int bc = tid; bc < NBC; bc += SC_THREADS) {
        const int n   = hist[bc];
        const int ls  = lstart[bc];
        const int gb  = gbase[bc];
        const int nch = (n + 7) >> 3;
        for (int jch = 0; jch < nch; ++jch) {
            const int gpos = gb + jch * CHUNK;
            if (gpos + CHUNK <= CAPC) {
                int2* dst = region + (size_t)bc * CAPC + gpos;
                #pragma unroll
                for (int j = 0; j < CHUNK; ++j) {
                    const int k = jch * CHUNK + j;
                    dst[j] = (k < n) ? stage[ls + k] : make_int2(-1, 0);
                }
            } else {
                // capacity overflow (rare): spill real entries
                for (int j = 0; j < CHUNK; ++j) {
                    const int k = jch * CHUNK + j;
                    if (k < n) {
                        const int2 t = stage[ls + k];
                        const int op = atomicAdd(ocount, 1);
                        if (op < OCAP)
                            overflow[op] = make_int4((bc << 8) | (t.x >> 17),
                                                     t.x & 0x1FFFF, t.y, 0);
                    }
                }
            }
        }
    }
}

// ---------- pass 2: FUSED per-bucket sort + gather ----------
// 1024 threads = 16 waves. Sort bucket into LDS (row-contiguous, full int2),
// then wave w gathers rows [w*16, w*16+16) straight from LDS.
__global__ __launch_bounds__(1024) void spmm_sort_gather(
    const int* __restrict__ gcnt,
    const int2* __restrict__ region,
    const float* __restrict__ x,
    float* __restrict__ out)
{
    __shared__ int2 srt[CAPC];         // 53.2 KB: (col, valbits) row-contiguous
    __shared__ int  hist[CBR];
    __shared__ int  startx[CBR];
    __shared__ int  cursor[CBR];

    const int bc  = blockIdx.x;
    const int tid = threadIdx.x;

    int n = gcnt[bc * 16]; if (n > CAPC) n = CAPC;   // written region = [0, min(gcnt,CAPC))
    const int2* __restrict__ slice = region + (size_t)bc * CAPC;

    if (tid < CBR) hist[tid] = 0;
    __syncthreads();

    for (int k = tid; k < n; k += 1024) {
        const int xv = slice[k].x;
        if (xv >= 0) atomicAdd(&hist[xv >> 17], 1);
    }
    __syncthreads();

    // inclusive Hillis-Steele scan over 256 row counts (threads 0..255 active)
    int h = 0;
    if (tid < CBR) { h = hist[tid]; startx[tid] = h; }
    __syncthreads();
    for (int off = 1; off < CBR; off <<= 1) {
        int v = 0;
        if (tid < CBR) { v = startx[tid]; if (tid >= off) v += startx[tid - off]; }
        __syncthreads();
        if (tid < CBR) startx[tid] = v;
        __syncthreads();
    }
    if (tid < CBR) cursor[tid] = startx[tid] - h;
    __syncthreads();

    // place real entries at row-sorted LDS position (full precision)
    for (int k = tid; k < n; k += 1024) {
        const int2 e = slice[k];
        if (e.x >= 0) {
            const int p = atomicAdd(&cursor[e.x >> 17], 1);
            srt[p] = make_int2(e.x & 0x1FFFF, e.y);   // (col, valbits)
        }
    }
    __syncthreads();

    // gather phase: wave w -> rows w*16 .. w*16+15; chain = x loads only
    const int wid  = tid >> 6;
    const int lane = tid & 63;
    const int eg   = lane >> 3;   // entry-slot 0..7
    const int d4   = lane & 7;    // float4 quarter of the row

    #pragma unroll
    for (int i = 0; i < 16; ++i) {
        const int lrow = wid * 16 + i;
        const int cnt  = hist[lrow];
        const int st   = startx[lrow] - cnt;   // exclusive start

        float4 acc = make_float4(0.f, 0.f, 0.f, 0.f);
        for (int k0 = 0; k0 < cnt; k0 += 16) {
            const int ka = k0 + eg;
            const int kb = ka + 8;
            const int2 ea = (ka < cnt) ? srt[st + ka] : make_int2(0, 0);
            const int2 eb = (kb < cnt) ? srt[st + kb] : make_int2(0, 0);
            const float va = __int_as_float(ea.y);   // sentinel val = 0
            const float vb = __int_as_float(eb.y);
            const float4 xa = *(const float4*)&x[ea.x * DIM + d4 * 4];
            const float4 xb = *(const float4*)&x[eb.x * DIM + d4 * 4];
            acc.x = fmaf(va, xa.x, acc.x);  acc.y = fmaf(va, xa.y, acc.y);
            acc.z = fmaf(va, xa.z, acc.z);  acc.w = fmaf(va, xa.w, acc.w);
            acc.x = fmaf(vb, xb.x, acc.x);  acc.y = fmaf(vb, xb.y, acc.y);
            acc.z = fmaf(vb, xb.z, acc.z);  acc.w = fmaf(vb, xb.w, acc.w);
        }

        // reduce the 8 entry-slots (xor 8,16,32 across the 64-lane wave)
        #pragma unroll
        for (int m = 8; m < 64; m <<= 1) {
            acc.x += __shfl_xor(acc.x, m, 64);
            acc.y += __shfl_xor(acc.y, m, 64);
            acc.z += __shfl_xor(acc.z, m, 64);
            acc.w += __shfl_xor(acc.w, m, 64);
        }

        const int r = bc * CBR + lrow;
        if (eg == 0 && r < N_NODES)
            *(float4*)&out[r * DIM + d4 * 4] = acc;   // covers every row; no out memset
    }
}

// ---------- pass 3: apply rare overflow edges (normally ~empty) ----------
__global__ __launch_bounds__(256) void spmm_overflow_apply(
    const int* __restrict__ ocount,
    const int4* __restrict__ overflow,
    const float* __restrict__ x,
    float* __restrict__ out)
{
    int n = *ocount;
    if (n > OCAP) n = OCAP;
    const long long total = (long long)n * DIM;
    for (long long idx = (long long)blockIdx.x * blockDim.x + threadIdx.x;
         idx < total; idx += (long long)gridDim.x * blockDim.x) {
        const int e = (int)(idx >> 5);
        const int d = (int)(idx & 31);
        const int4 t = overflow[e];
        atomicAdd(&out[(long long)t.x * DIM + d],
                  __int_as_float(t.z) * x[(long long)t.y * DIM + d]);
    }
}

extern "C" void kernel_launch(void* const* d_in, const int* in_sizes, int n_in,
                              void* d_out, int out_size, void* d_ws, size_t ws_size,
                              hipStream_t stream) {
    const int*   A_rows = (const int*)d_in[0];
    const int*   A_cols = (const int*)d_in[1];
    const float* A_vals = (const float*)d_in[2];
    const float* x      = (const float*)d_in[3];
    float*       out    = (float*)d_out;

    if (d_ws == nullptr || ws_size < WS_NEEDED) {
        // workspace too small: original verified atomic path (needs zeroed out)
        hipMemsetAsync(out, 0, (size_t)out_size * sizeof(float), stream);
        const long long total = (long long)N_EDGES * DIM;
        const int block = 256;
        const long long grid = (total + block - 1) / block;
        spmm_atomic_kernel<<<(dim3)(unsigned)grid, block, 0, stream>>>(
            A_rows, A_cols, A_vals, x, out);
        return;
    }

    char* ws = (char*)d_ws;
    int*  ocount   = (int*)ws;
    int*  gcnt     = (int*)(ws + OFF_GCNT);
    int4* overflow = (int4*)(ws + OFF_OVER);
    int2* region   = (int2*)(ws + OFF_REGION);

    // zero ocount + padded gcnt (25 KB); out fully written by pass 2
    hipMemsetAsync(ws, 0, OFF_OVER, stream);

    spmm_scatter_ws<<<SC_BLOCKS, SC_THREADS, 0, stream>>>(
        A_rows, A_cols, A_vals, gcnt, region, ocount, overflow);

    spmm_sort_gather<<<NBC, 1024, 0, stream>>>(gcnt, region, x, out);

    spmm_overflow_apply<<<64, 256, 0, stream>>>(ocount, overflow, x, out);
}

// Round 10
// 133.178 us; speedup vs baseline: 1.5577x; 1.0281x over previous
//
#include <hip/hip_runtime.h>

// SpMM: out[i,d] = sum_{e: rows[e]==i} vals[e] * x[cols[e], d]
// N=100000 nodes, E=1600000 edges, DIM=32, fp32.
//
// v11: v10 + register-staged sort (single region read) + shfl scans + fused overflow.
//  v10 post-mortem: all kernels below harness-fill cutoff; ~67us GPU pipeline
//  vs ~35us BW floor. Remaining waste is protocol: (1) sort_gather read the
//  region slice TWICE (hist pass + placement pass, 2x21MB); (2) Hillis-Steele
//  scans cost 16-18 barriers per block; (3) overflow_apply was a dedicated
//  launch for a normally-empty list.
//  v11: (1) slice register-staged (7 int2/thread, scatter-proven pattern),
//  hist+placement from registers -> one global read; (2) both scans are
//  2-level __shfl_up wave scans (2 barriers); (3) overflow folded into
//  sort_gather tail (after out stores + barrier -> vmcnt drained -> same-XCD
//  L2 ordering makes plain-store-then-atomicAdd safe).
//    pass1 scatter (v8 WC + shfl scan)
//    pass2 fused sort+gather+overflow -> out   (3 launches total + memset)
//
//  ws layout (~21.1 MB):
//   [0     .. 64)     : ocount
//   [64    .. 25088)  : gcnt, NBC x 64B-padded int
//   [25088 .. 287K)   : overflow, OCAP x int4 {r,c,valbits,_}
//   [~287K .. ~21.1M) : region, NBC x CAPC x int2 {(lrow<<17)|col, valbits}

#define N_NODES 100000
#define N_EDGES 1600000
#define DIM 32

#define CBR    256                         // rows per coarse bucket
#define NBC    ((N_NODES + CBR - 1) / CBR) // 391
#define CHUNK  8                           // 8 x int2 = 64B line
#define CAPC   6656                        // entries/bucket (mean ~5751 incl pad, +8 sigma)
#define OCAP   16384

#define SC_BLOCKS   500
#define SC_THREADS  512
#define EPB         3200                   // edges per block: 500*3200 = 1.6M exactly
#define EPT         7                      // ceil(3200/512)

#define SG_THREADS  1024
#define SG_EPT      7                      // ceil(CAPC/1024)

#define OFF_GCNT    64
#define OFF_OVER    (OFF_GCNT + NBC * 64)                     // 25088
#define OFF_REGION  (((OFF_OVER + OCAP * 16) + 255) & ~255)
#define WS_NEEDED   ((size_t)OFF_REGION + (size_t)NBC * CAPC * 8)

// ---------- fallback: original verified kernel (thread per (edge,dim)) ----------
__global__ __launch_bounds__(256) void spmm_atomic_kernel(
    const int* __restrict__ rows,
    const int* __restrict__ cols,
    const float* __restrict__ vals,
    const float* __restrict__ x,
    float* __restrict__ out)
{
    const long long idx = (long long)blockIdx.x * blockDim.x + threadIdx.x;
    const long long total = (long long)N_EDGES * DIM;
    if (idx >= total) return;

    const int e = (int)(idx >> 5);
    const int d = (int)(idx & 31);

    const int r   = rows[e];
    const int c   = cols[e];
    const float v = vals[e];

    const float xv = x[(long long)c * DIM + d];
    atomicAdd(&out[(long long)r * DIM + d], v * xv);
}

// ---------- pass 1: single-round register-staged WC scatter (v8 + shfl scan) ----------
__global__ __launch_bounds__(SC_THREADS) void spmm_scatter_ws(
    const int* __restrict__ rows,
    const int* __restrict__ cols,
    const float* __restrict__ vals,
    int* __restrict__ gcnt,          // NBC cursors, 64B-padded (index *16)
    int2* __restrict__ region,       // NBC x CAPC
    int* __restrict__ ocount,
    int4* __restrict__ overflow)
{
    __shared__ int2 stage[EPB];      // 25.6 KB, bucket-contiguous staging
    __shared__ int  hist[NBC];
    __shared__ int  lstart[NBC];     // LDS segment start per bucket
    __shared__ int  cursor[NBC];
    __shared__ int  gbase[NBC];      // global reservation per bucket
    __shared__ int  wsum[8];         // per-wave scan sums

    const int tid   = threadIdx.x;
    const int ebase = blockIdx.x * EPB;

    if (tid < NBC) hist[tid] = 0;
    __syncthreads();

    // load edges into registers (compile-time indices -> stays in VGPRs), histogram
    int en_x[EPT], en_y[EPT], eb[EPT];
    #pragma unroll
    for (int i = 0; i < EPT; ++i) {
        const int o = i * SC_THREADS + tid;
        if (o < EPB) {
            const int e = ebase + o;
            const int r = rows[e];
            eb[i]   = r >> 8;
            en_x[i] = ((r & 255) << 17) | cols[e];
            en_y[i] = __float_as_int(vals[e]);
            atomicAdd(&hist[eb[i]], 1);
        } else {
            eb[i] = -1; en_x[i] = 0; en_y[i] = 0;
        }
    }
    __syncthreads();

    // 2-level shfl scan over NBC (padded to 512): 2 barriers, no LDS ping-pong
    const int lane = tid & 63;
    const int wv   = tid >> 6;
    const int myh  = (tid < NBC) ? hist[tid] : 0;
    int s = myh;
    #pragma unroll
    for (int off = 1; off < 64; off <<= 1) {
        const int t = __shfl_up(s, off, 64);
        if (lane >= off) s += t;
    }
    if (lane == 63) wsum[wv] = s;
    __syncthreads();
    if (wv == 0) {
        const int t = (lane < 8) ? wsum[lane] : 0;
        int ss = t;
        #pragma unroll
        for (int off = 1; off < 8; off <<= 1) {
            const int u = __shfl_up(ss, off, 64);
            if (lane >= off) ss += u;
        }
        if (lane < 8) wsum[lane] = ss - t;   // exclusive wave offset
    }
    __syncthreads();
    if (tid < NBC) {
        const int excl = s + wsum[wv] - myh;
        lstart[tid] = excl;
        cursor[tid] = excl;
        const int pad = (myh + 7) & ~7;
        // ONE reservation per (block,bucket); 64B-padded counter -> no line contention
        gbase[tid] = pad ? atomicAdd(&gcnt[tid * 16], pad) : 0;
    }
    __syncthreads();

    // place register-staged entries into bucket-contiguous LDS
    #pragma unroll
    for (int i = 0; i < EPT; ++i) {
        if (eb[i] >= 0) {
            const int p = atomicAdd(&cursor[eb[i]], 1);
            stage[p] = make_int2(en_x[i], en_y[i]);
        }
    }
    __syncthreads();

    // flush: full 64B lines only (sentinel pad), one-lane bursts (v7-proven WC)
    for (int bc = tid; bc < NBC; bc += SC_THREADS) {
        const int n   = hist[bc];
        const int ls  = lstart[bc];
        const int gb  = gbase[bc];
        const int nch = (n + 7) >> 3;
        for (int jch = 0; jch < nch; ++jch) {
            const int gpos = gb + jch * CHUNK;
            if (gpos + CHUNK <= CAPC) {
                int2* dst = region + (size_t)bc * CAPC + gpos;
                #pragma unroll
                for (int j = 0; j < CHUNK; ++j) {
                    const int k = jch * CHUNK + j;
                    dst[j] = (k < n) ? stage[ls + k] : make_int2(-1, 0);
                }
            } else {
                // capacity overflow (rare): spill real entries
                for (int j = 0; j < CHUNK; ++j) {
                    const int k = jch * CHUNK + j;
                    if (k < n) {
                        const int2 t = stage[ls + k];
                        const int op = atomicAdd(ocount, 1);
                        if (op < OCAP)
                            overflow[op] = make_int4((bc << 8) | (t.x >> 17),
                                                     t.x & 0x1FFFF, t.y, 0);
                    }
                }
            }
        }
    }
}

// ---------- pass 2: FUSED per-bucket sort + gather + overflow ----------
// 1024 threads = 16 waves. Register-stage slice (ONE global read), shfl-scan,
// sort into LDS, then wave w gathers rows [w*16, w*16+16) from LDS; finally
// apply this bucket's overflow entries (normally none).
__global__ __launch_bounds__(SG_THREADS) void spmm_sort_gather(
    const int* __restrict__ gcnt,
    const int2* __restrict__ region,
    const int* __restrict__ ocount,
    const int4* __restrict__ overflow,
    const float* __restrict__ x,
    float* __restrict__ out)
{
    __shared__ int2 srt[CAPC];         // 53.2 KB: (col, valbits) row-contiguous
    __shared__ int  hist[CBR];
    __shared__ int  startx[CBR];       // inclusive scan
    __shared__ int  cursor[CBR];
    __shared__ int  wsum[4];

    const int bc  = blockIdx.x;
    const int tid = threadIdx.x;

    int n = gcnt[bc * 16]; if (n > CAPC) n = CAPC;   // written region = [0, min(gcnt,CAPC))
    const int2* __restrict__ slice = region + (size_t)bc * CAPC;

    if (tid < CBR) hist[tid] = 0;
    __syncthreads();

    // register-stage the slice + histogram: SINGLE global read of the region
    int ex[SG_EPT], ey[SG_EPT];
    #pragma unroll
    for (int i = 0; i < SG_EPT; ++i) {
        const int k = i * SG_THREADS + tid;
        ex[i] = -1; ey[i] = 0;
        if (k < n) {
            const int2 e = slice[k];
            ex[i] = e.x; ey[i] = e.y;
            if (e.x >= 0) atomicAdd(&hist[e.x >> 17], 1);
        }
    }
    __syncthreads();

    // shfl scan over 256 hist values (waves 0..3 exactly cover tid<256)
    const int lane = tid & 63;
    const int wv   = tid >> 6;
    int h = 0, incl = 0;
    if (tid < CBR) {
        h = hist[tid];
        int s = h;
        #pragma unroll
        for (int off = 1; off < 64; off <<= 1) {
            const int t = __shfl_up(s, off, 64);
            if (lane >= off) s += t;
        }
        incl = s;
        if (lane == 63) wsum[wv] = s;
    }
    __syncthreads();
    if (wv == 0) {
        const int t = (lane < 4) ? wsum[lane] : 0;
        int ss = t;
        #pragma unroll
        for (int off = 1; off < 4; off <<= 1) {
            const int u = __shfl_up(ss, off, 64);
            if (lane >= off) ss += u;
        }
        if (lane < 4) wsum[lane] = ss - t;   // exclusive wave offset
    }
    __syncthreads();
    if (tid < CBR) {
        incl += wsum[wv];
        startx[tid] = incl;
        cursor[tid] = incl - h;
    }
    __syncthreads();

    // place from registers at row-sorted LDS position (full precision)
    #pragma unroll
    for (int i = 0; i < SG_EPT; ++i) {
        if (ex[i] >= 0) {
            const int p = atomicAdd(&cursor[ex[i] >> 17], 1);
            srt[p] = make_int2(ex[i] & 0x1FFFF, ey[i]);   // (col, valbits)
        }
    }
    __syncthreads();

    // gather phase: wave w -> rows w*16 .. w*16+15; chain = x loads only
    const int wid = tid >> 6;
    const int eg  = lane >> 3;   // entry-slot 0..7
    const int d4  = lane & 7;    // float4 quarter of the row

    #pragma unroll
    for (int i = 0; i < 16; ++i) {
        const int lrow = wid * 16 + i;
        const int cnt  = hist[lrow];
        const int st   = startx[lrow] - cnt;   // exclusive start

        float4 acc = make_float4(0.f, 0.f, 0.f, 0.f);
        for (int k0 = 0; k0 < cnt; k0 += 16) {
            const int ka = k0 + eg;
            const int kb = ka + 8;
            const int2 ea = (ka < cnt) ? srt[st + ka] : make_int2(0, 0);
            const int2 eb = (kb < cnt) ? srt[st + kb] : make_int2(0, 0);
            const float va = __int_as_float(ea.y);   // sentinel val = 0
            const float vb = __int_as_float(eb.y);
            const float4 xa = *(const float4*)&x[ea.x * DIM + d4 * 4];
            const float4 xb = *(const float4*)&x[eb.x * DIM + d4 * 4];
            acc.x = fmaf(va, xa.x, acc.x);  acc.y = fmaf(va, xa.y, acc.y);
            acc.z = fmaf(va, xa.z, acc.z);  acc.w = fmaf(va, xa.w, acc.w);
            acc.x = fmaf(vb, xb.x, acc.x);  acc.y = fmaf(vb, xb.y, acc.y);
            acc.z = fmaf(vb, xb.z, acc.z);  acc.w = fmaf(vb, xb.w, acc.w);
        }

        // reduce the 8 entry-slots (xor 8,16,32 across the 64-lane wave)
        #pragma unroll
        for (int m = 8; m < 64; m <<= 1) {
            acc.x += __shfl_xor(acc.x, m, 64);
            acc.y += __shfl_xor(acc.y, m, 64);
            acc.z += __shfl_xor(acc.z, m, 64);
            acc.w += __shfl_xor(acc.w, m, 64);
        }

        const int r = bc * CBR + lrow;
        if (eg == 0 && r < N_NODES)
            *(float4*)&out[r * DIM + d4 * 4] = acc;   // covers every row; no out memset
    }

    // fused overflow apply: barrier drains the out stores (vmcnt(0)) before
    // any RMW on the same rows; same block = same XCD L2 => ordered.
    __syncthreads();
    int on = *ocount;
    if (on > 0) {
        if (on > OCAP) on = OCAP;
        for (int k = tid; k < on; k += SG_THREADS) {
            const int4 t = overflow[k];
            if ((t.x >> 8) == bc) {
                const float v = __int_as_float(t.z);
                const float* __restrict__ xr = x + (long long)t.y * DIM;
                float* orow = out + (long long)t.x * DIM;
                for (int d = 0; d < DIM; ++d)
                    atomicAdd(&orow[d], v * xr[d]);
            }
        }
    }
}

extern "C" void kernel_launch(void* const* d_in, const int* in_sizes, int n_in,
                              void* d_out, int out_size, void* d_ws, size_t ws_size,
                              hipStream_t stream) {
    const int*   A_rows = (const int*)d_in[0];
    const int*   A_cols = (const int*)d_in[1];
    const float* A_vals = (const float*)d_in[2];
    const float* x      = (const float*)d_in[3];
    float*       out    = (float*)d_out;

    if (d_ws == nullptr || ws_size < WS_NEEDED) {
        // workspace too small: original verified atomic path (needs zeroed out)
        hipMemsetAsync(out, 0, (size_t)out_size * sizeof(float), stream);
        const long long total = (long long)N_EDGES * DIM;
        const int block = 256;
        const long long grid = (total + block - 1) / block;
        spmm_atomic_kernel<<<(dim3)(unsigned)grid, block, 0, stream>>>(
            A_rows, A_cols, A_vals, x, out);
        return;
    }

    char* ws = (char*)d_ws;
    int*  ocount   = (int*)ws;
    int*  gcnt     = (int*)(ws + OFF_GCNT);
    int4* overflow = (int4*)(ws + OFF_OVER);
    int2* region   = (int2*)(ws + OFF_REGION);

    // zero ocount + padded gcnt (25 KB); out fully written by pass 2
    hipMemsetAsync(ws, 0, OFF_OVER, stream);

    spmm_scatter_ws<<<SC_BLOCKS, SC_THREADS, 0, stream>>>(
        A_rows, A_cols, A_vals, gcnt, region, ocount, overflow);

    spmm_sort_gather<<<NBC, SG_THREADS, 0, stream>>>(
        gcnt, region, ocount, overflow, x, out);
}

// Round 11
// 132.257 us; speedup vs baseline: 1.5685x; 1.0070x over previous
//
#include <hip/hip_runtime.h>

// SpMM: out[i,d] = sum_{e: rows[e]==i} vals[e] * x[cols[e], d]
// N=100000 nodes, E=1600000 edges, DIM=32, fp32.
//
// v12: v11 + rank-from-histogram (single LDS-atomic pass per kernel).
//  v11 post-mortem: +3.7us only; remaining pipeline ~55-60us vs ~20us BW
//  floor -> protocol slack. Both kernels did TWO per-edge LDS atomic passes
//  (histogram + returning-cursor placement) = ~6.4M LDS atomics grid-wide;
//  returning-atomic+dependent-write chains are the proven-expensive pattern
//  (v4). v12 keeps the histogram atomic's RETURN VALUE as the edge's dense
//  per-bucket rank; after the scan, placement is a pure LDS write at
//  lstart[b]+rk. Cursor pass deleted in BOTH kernels.
//    pass1 scatter (v8 WC, 1 atomic pass)
//    pass2 fused sort+gather+overflow (1 atomic pass)  [3 dispatches total]
//
//  ws layout (~21.1 MB):
//   [0     .. 64)     : ocount
//   [64    .. 25088)  : gcnt, NBC x 64B-padded int
//   [25088 .. 287K)   : overflow, OCAP x int4 {r,c,valbits,_}
//   [~287K .. ~21.1M) : region, NBC x CAPC x int2 {(lrow<<17)|col, valbits}

#define N_NODES 100000
#define N_EDGES 1600000
#define DIM 32

#define CBR    256                         // rows per coarse bucket
#define NBC    ((N_NODES + CBR - 1) / CBR) // 391
#define CHUNK  8                           // 8 x int2 = 64B line
#define CAPC   6656                        // entries/bucket (mean ~5751 incl pad, +8 sigma)
#define OCAP   16384

#define SC_BLOCKS   500
#define SC_THREADS  512
#define EPB         3200                   // edges per block: 500*3200 = 1.6M exactly
#define EPT         7                      // ceil(3200/512)

#define SG_THREADS  1024
#define SG_EPT      7                      // ceil(CAPC/1024)

#define OFF_GCNT    64
#define OFF_OVER    (OFF_GCNT + NBC * 64)                     // 25088
#define OFF_REGION  (((OFF_OVER + OCAP * 16) + 255) & ~255)
#define WS_NEEDED   ((size_t)OFF_REGION + (size_t)NBC * CAPC * 8)

// ---------- fallback: original verified kernel (thread per (edge,dim)) ----------
__global__ __launch_bounds__(256) void spmm_atomic_kernel(
    const int* __restrict__ rows,
    const int* __restrict__ cols,
    const float* __restrict__ vals,
    const float* __restrict__ x,
    float* __restrict__ out)
{
    const long long idx = (long long)blockIdx.x * blockDim.x + threadIdx.x;
    const long long total = (long long)N_EDGES * DIM;
    if (idx >= total) return;

    const int e = (int)(idx >> 5);
    const int d = (int)(idx & 31);

    const int r   = rows[e];
    const int c   = cols[e];
    const float v = vals[e];

    const float xv = x[(long long)c * DIM + d];
    atomicAdd(&out[(long long)r * DIM + d], v * xv);
}

// ---------- pass 1: register-staged WC scatter, single LDS-atomic pass ----------
__global__ __launch_bounds__(SC_THREADS) void spmm_scatter_ws(
    const int* __restrict__ rows,
    const int* __restrict__ cols,
    const float* __restrict__ vals,
    int* __restrict__ gcnt,          // NBC cursors, 64B-padded (index *16)
    int2* __restrict__ region,       // NBC x CAPC
    int* __restrict__ ocount,
    int4* __restrict__ overflow)
{
    __shared__ int2 stage[EPB];      // 25.6 KB, bucket-contiguous staging
    __shared__ int  hist[NBC];
    __shared__ int  lstart[NBC];     // LDS segment start per bucket (exclusive)
    __shared__ int  gbase[NBC];      // global reservation per bucket
    __shared__ int  wsum[8];         // per-wave scan sums

    const int tid   = threadIdx.x;
    const int ebase = blockIdx.x * EPB;

    if (tid < NBC) hist[tid] = 0;
    __syncthreads();

    // load edges into registers + histogram; KEEP the atomic's return = rank
    int en_x[EPT], en_y[EPT], eb[EPT], rk[EPT];
    #pragma unroll
    for (int i = 0; i < EPT; ++i) {
        const int o = i * SC_THREADS + tid;
        if (o < EPB) {
            const int e = ebase + o;
            const int r = rows[e];
            eb[i]   = r >> 8;
            en_x[i] = ((r & 255) << 17) | cols[e];
            en_y[i] = __float_as_int(vals[e]);
            rk[i]   = atomicAdd(&hist[eb[i]], 1);   // dense per-bucket rank
        } else {
            eb[i] = -1; en_x[i] = 0; en_y[i] = 0; rk[i] = 0;
        }
    }
    __syncthreads();

    // 2-level shfl scan over NBC (padded to 512): 2 barriers, no LDS ping-pong
    const int lane = tid & 63;
    const int wv   = tid >> 6;
    const int myh  = (tid < NBC) ? hist[tid] : 0;
    int s = myh;
    #pragma unroll
    for (int off = 1; off < 64; off <<= 1) {
        const int t = __shfl_up(s, off, 64);
        if (lane >= off) s += t;
    }
    if (lane == 63) wsum[wv] = s;
    __syncthreads();
    if (wv == 0) {
        const int t = (lane < 8) ? wsum[lane] : 0;
        int ss = t;
        #pragma unroll
        for (int off = 1; off < 8; off <<= 1) {
            const int u = __shfl_up(ss, off, 64);
            if (lane >= off) ss += u;
        }
        if (lane < 8) wsum[lane] = ss - t;   // exclusive wave offset
    }
    __syncthreads();
    if (tid < NBC) {
        lstart[tid] = s + wsum[wv] - myh;
        const int pad = (myh + 7) & ~7;
        // ONE reservation per (block,bucket); 64B-padded counter -> no line contention
        gbase[tid] = pad ? atomicAdd(&gcnt[tid * 16], pad) : 0;
    }
    __syncthreads();

    // placement: PURE LDS write at lstart + rank (cursor pass deleted)
    #pragma unroll
    for (int i = 0; i < EPT; ++i) {
        if (eb[i] >= 0)
            stage[lstart[eb[i]] + rk[i]] = make_int2(en_x[i], en_y[i]);
    }
    __syncthreads();

    // flush: full 64B lines only (sentinel pad), one-lane bursts (v7-proven WC)
    for (int bc = tid; bc < NBC; bc += SC_THREADS) {
        const int n   = hist[bc];
        const int ls  = lstart[bc];
        const int gb  = gbase[bc];
        const int nch = (n + 7) >> 3;
        for (int jch = 0; jch < nch; ++jch) {
            const int gpos = gb + jch * CHUNK;
            if (gpos + CHUNK <= CAPC) {
                int2* dst = region + (size_t)bc * CAPC + gpos;
                #pragma unroll
                for (int j = 0; j < CHUNK; ++j) {
                    const int k = jch * CHUNK + j;
                    dst[j] = (k < n) ? stage[ls + k] : make_int2(-1, 0);
                }
            } else {
                // capacity overflow (rare): spill real entries
                for (int j = 0; j < CHUNK; ++j) {
                    const int k = jch * CHUNK + j;
                    if (k < n) {
                        const int2 t = stage[ls + k];
                        const int op = atomicAdd(ocount, 1);
                        if (op < OCAP)
                            overflow[op] = make_int4((bc << 8) | (t.x >> 17),
                                                     t.x & 0x1FFFF, t.y, 0);
                    }
                }
            }
        }
    }
}

// ---------- pass 2: FUSED per-bucket sort + gather + overflow (1 atomic pass) ----------
__global__ __launch_bounds__(SG_THREADS) void spmm_sort_gather(
    const int* __restrict__ gcnt,
    const int2* __restrict__ region,
    const int* __restrict__ ocount,
    const int4* __restrict__ overflow,
    const float* __restrict__ x,
    float* __restrict__ out)
{
    __shared__ int2 srt[CAPC];         // 53.2 KB: (col, valbits) row-contiguous
    __shared__ int  hist[CBR];
    __shared__ int  startx[CBR];       // inclusive scan
    __shared__ int  excl_s[CBR];       // exclusive starts
    __shared__ int  wsum[4];

    const int bc  = blockIdx.x;
    const int tid = threadIdx.x;

    int n = gcnt[bc * 16]; if (n > CAPC) n = CAPC;   // written region = [0, min(gcnt,CAPC))
    const int2* __restrict__ slice = region + (size_t)bc * CAPC;

    if (tid < CBR) hist[tid] = 0;
    __syncthreads();

    // register-stage the slice (single region read) + histogram WITH rank capture
    int ex[SG_EPT], ey[SG_EPT], rk[SG_EPT];
    #pragma unroll
    for (int i = 0; i < SG_EPT; ++i) {
        const int k = i * SG_THREADS + tid;
        ex[i] = -1; ey[i] = 0; rk[i] = 0;
        if (k < n) {
            const int2 e = slice[k];
            ex[i] = e.x; ey[i] = e.y;
            if (e.x >= 0) rk[i] = atomicAdd(&hist[e.x >> 17], 1);
        }
    }
    __syncthreads();

    // shfl scan over 256 hist values (waves 0..3 exactly cover tid<256)
    const int lane = tid & 63;
    const int wv   = tid >> 6;
    int h = 0, incl = 0;
    if (tid < CBR) {
        h = hist[tid];
        int s = h;
        #pragma unroll
        for (int off = 1; off < 64; off <<= 1) {
            const int t = __shfl_up(s, off, 64);
            if (lane >= off) s += t;
        }
        incl = s;
        if (lane == 63) wsum[wv] = s;
    }
    __syncthreads();
    if (wv == 0) {
        const int t = (lane < 4) ? wsum[lane] : 0;
        int ss = t;
        #pragma unroll
        for (int off = 1; off < 4; off <<= 1) {
            const int u = __shfl_up(ss, off, 64);
            if (lane >= off) ss += u;
        }
        if (lane < 4) wsum[lane] = ss - t;   // exclusive wave offset
    }
    __syncthreads();
    if (tid < CBR) {
        incl += wsum[wv];
        startx[tid] = incl;
        excl_s[tid] = incl - h;
    }
    __syncthreads();

    // placement: PURE LDS write at excl + rank (cursor pass deleted)
    #pragma unroll
    for (int i = 0; i < SG_EPT; ++i) {
        if (ex[i] >= 0)
            srt[excl_s[ex[i] >> 17] + rk[i]] = make_int2(ex[i] & 0x1FFFF, ey[i]);
    }
    __syncthreads();

    // gather phase: wave w -> rows w*16 .. w*16+15; chain = x loads only
    const int wid = tid >> 6;
    const int eg  = lane >> 3;   // entry-slot 0..7
    const int d4  = lane & 7;    // float4 quarter of the row

    #pragma unroll
    for (int i = 0; i < 16; ++i) {
        const int lrow = wid * 16 + i;
        const int cnt  = hist[lrow];
        const int st   = startx[lrow] - cnt;   // exclusive start

        float4 acc = make_float4(0.f, 0.f, 0.f, 0.f);
        for (int k0 = 0; k0 < cnt; k0 += 16) {
            const int ka = k0 + eg;
            const int kb = ka + 8;
            const int2 ea = (ka < cnt) ? srt[st + ka] : make_int2(0, 0);
            const int2 eb = (kb < cnt) ? srt[st + kb] : make_int2(0, 0);
            const float va = __int_as_float(ea.y);   // sentinel val = 0
            const float vb = __int_as_float(eb.y);
            const float4 xa = *(const float4*)&x[ea.x * DIM + d4 * 4];
            const float4 xb = *(const float4*)&x[eb.x * DIM + d4 * 4];
            acc.x = fmaf(va, xa.x, acc.x);  acc.y = fmaf(va, xa.y, acc.y);
            acc.z = fmaf(va, xa.z, acc.z);  acc.w = fmaf(va, xa.w, acc.w);
            acc.x = fmaf(vb, xb.x, acc.x);  acc.y = fmaf(vb, xb.y, acc.y);
            acc.z = fmaf(vb, xb.z, acc.z);  acc.w = fmaf(vb, xb.w, acc.w);
        }

        // reduce the 8 entry-slots (xor 8,16,32 across the 64-lane wave)
        #pragma unroll
        for (int m = 8; m < 64; m <<= 1) {
            acc.x += __shfl_xor(acc.x, m, 64);
            acc.y += __shfl_xor(acc.y, m, 64);
            acc.z += __shfl_xor(acc.z, m, 64);
            acc.w += __shfl_xor(acc.w, m, 64);
        }

        const int r = bc * CBR + lrow;
        if (eg == 0 && r < N_NODES)
            *(float4*)&out[r * DIM + d4 * 4] = acc;   // covers every row; no out memset
    }

    // fused overflow apply: barrier drains the out stores before any RMW
    __syncthreads();
    int on = *ocount;
    if (on > 0) {
        if (on > OCAP) on = OCAP;
        for (int k = tid; k < on; k += SG_THREADS) {
            const int4 t = overflow[k];
            if ((t.x >> 8) == bc) {
                const float v = __int_as_float(t.z);
                const float* __restrict__ xr = x + (long long)t.y * DIM;
                float* orow = out + (long long)t.x * DIM;
                for (int d = 0; d < DIM; ++d)
                    atomicAdd(&orow[d], v * xr[d]);
            }
        }
    }
}

extern "C" void kernel_launch(void* const* d_in, const int* in_sizes, int n_in,
                              void* d_out, int out_size, void* d_ws, size_t ws_size,
                              hipStream_t stream) {
    const int*   A_rows = (const int*)d_in[0];
    const int*   A_cols = (const int*)d_in[1];
    const float* A_vals = (const float*)d_in[2];
    const float* x      = (const float*)d_in[3];
    float*       out    = (float*)d_out;

    if (d_ws == nullptr || ws_size < WS_NEEDED) {
        // workspace too small: original verified atomic path (needs zeroed out)
        hipMemsetAsync(out, 0, (size_t)out_size * sizeof(float), stream);
        const long long total = (long long)N_EDGES * DIM;
        const int block = 256;
        const long long grid = (total + block - 1) / block;
        spmm_atomic_kernel<<<(dim3)(unsigned)grid, block, 0, stream>>>(
            A_rows, A_cols, A_vals, x, out);
        return;
    }

    char* ws = (char*)d_ws;
    int*  ocount   = (int*)ws;
    int*  gcnt     = (int*)(ws + OFF_GCNT);
    int4* overflow = (int4*)(ws + OFF_OVER);
    int2* region   = (int2*)(ws + OFF_REGION);

    // zero ocount + padded gcnt (25 KB); out fully written by pass 2
    hipMemsetAsync(ws, 0, OFF_OVER, stream);

    spmm_scatter_ws<<<SC_BLOCKS, SC_THREADS, 0, stream>>>(
        A_rows, A_cols, A_vals, gcnt, region, ocount, overflow);

    spmm_sort_gather<<<NBC, SG_THREADS, 0, stream>>>(
        gcnt, region, ocount, overflow, x, out);
}